// Round 8
// baseline (142.067 us; speedup 1.0000x reference)
//
#include <hip/hip_runtime.h>
#include <hip/hip_bf16.h>
#include <stdint.h>

// Problem dims (fixed by setup_inputs)
#define B_N 4096
#define S_N 8192
#define KX  256
#define KY  128
// Tiling: 256x128 (batch x sample) tile per block, K fused (256 x + 128 y), BK=32
// 8 waves in 4x2 grid, each wave owns a 64x64 output sub-tile (2 streams).
#define BM 256
#define BN 128

typedef __bf16 bf16x8 __attribute__((ext_vector_type(8)));
typedef float  f32x4  __attribute__((ext_vector_type(4)));

// ---- workspace byte offsets ----
#define OFF_XH   ((size_t)0)            // 4096*256*2 = 2 MB
#define OFF_YH   ((size_t)2097152)      // 4096*128*2 = 1 MB
#define OFF_SXH  ((size_t)3145728)      // 8192*256*2 = 4 MB
#define OFF_SYH  ((size_t)7340032)      // 8192*128*2 = 2 MB
#define OFF_NX   ((size_t)9437184)      // 4096 f32
#define OFF_NY   (OFF_NX + 16384)
#define OFF_NSX  (OFF_NY + 16384)       // 8192 f32
#define OFF_NSY  (OFF_NSX + 32768)
#define OFF_PART (OFF_NSY + 32768)      // [3][64][4096] float2 = 6.29 MB
#define OFF_BSUM (OFF_PART + (size_t)3*64*4096*2*4)   // [0]=done u32, [1]=fsum f32

__device__ __forceinline__ void gl2lds16(const void* g, void* l) {
  // async global->LDS, 16B per lane; LDS dest = wave-uniform base + lane*16
  typedef const __attribute__((address_space(1))) unsigned int* gp_t;
  typedef __attribute__((address_space(3))) unsigned int* lp_t;
  __builtin_amdgcn_global_load_lds((gp_t)g, (lp_t)l, 16, 0, 0);
}

__device__ __forceinline__ unsigned short f2bf(float f) {
  unsigned u = __builtin_bit_cast(unsigned, f);
  return (unsigned short)((u + 0x7fffu + ((u >> 16) & 1u)) >> 16);
}

// ---- preprocessing v2: fp32 -> bf16 + fp32 row norms, 4 rows/wave ILP ----
__global__ __launch_bounds__(256) void conv_all(const float* __restrict__ x,
                                                const float* __restrict__ y,
                                                const float* __restrict__ xs,
                                                const float* __restrict__ ys,
                                                char* __restrict__ ws) {
  int b    = blockIdx.x;
  int wave = threadIdx.x >> 6;
  int lane = threadIdx.x & 63;
  if (b == 0 && threadIdx.x < 2) ((unsigned*)(ws + OFF_BSUM))[threadIdx.x] = 0u;
  const float* src; unsigned short* hi; float* nrm;
  int K, r0;
  if (b < 256) {
    src = x;  hi = (unsigned short*)(ws + OFF_XH);
    nrm = (float*)(ws + OFF_NX);  K = 256; r0 = b * 16 + wave * 4;
  } else if (b < 512) {
    src = y;  hi = (unsigned short*)(ws + OFF_YH);
    nrm = (float*)(ws + OFF_NY);  K = 128; r0 = (b - 256) * 16 + wave * 4;
  } else if (b < 1024) {
    src = xs; hi = (unsigned short*)(ws + OFF_SXH);
    nrm = (float*)(ws + OFF_NSX); K = 256; r0 = (b - 512) * 16 + wave * 4;
  } else {
    src = ys; hi = (unsigned short*)(ws + OFF_SYH);
    nrm = (float*)(ws + OFF_NSY); K = 128; r0 = (b - 1024) * 16 + wave * 4;
  }
  if (K == 256) {
    float4 v[4];
    #pragma unroll
    for (int j = 0; j < 4; ++j)
      v[j] = ((const float4*)(src + (size_t)(r0 + j) * 256))[lane];
    #pragma unroll
    for (int j = 0; j < 4; ++j) {
      float vv[4] = {v[j].x, v[j].y, v[j].z, v[j].w};
      ushort4 h4;
      unsigned short* hp = (unsigned short*)&h4;
      float acc = 0.f;
      #pragma unroll
      for (int k = 0; k < 4; ++k) {
        hp[k] = f2bf(vv[k]);
        acc = fmaf(vv[k], vv[k], acc);
      }
      ((ushort4*)(hi + (size_t)(r0 + j) * 256))[lane] = h4;
      #pragma unroll
      for (int o = 32; o > 0; o >>= 1) acc += __shfl_down(acc, o);
      if (lane == 0) nrm[r0 + j] = acc;
    }
  } else {
    float2 v[4];
    #pragma unroll
    for (int j = 0; j < 4; ++j)
      v[j] = ((const float2*)(src + (size_t)(r0 + j) * 128))[lane];
    #pragma unroll
    for (int j = 0; j < 4; ++j) {
      float vv[2] = {v[j].x, v[j].y};
      ushort2 h2;
      unsigned short* hp = (unsigned short*)&h2;
      float acc = 0.f;
      #pragma unroll
      for (int k = 0; k < 2; ++k) {
        hp[k] = f2bf(vv[k]);
        acc = fmaf(vv[k], vv[k], acc);
      }
      ((ushort2*)(hi + (size_t)(r0 + j) * 128))[lane] = h2;
      #pragma unroll
      for (int o = 32; o > 0; o >>= 1) acc += __shfl_down(acc, o);
      if (lane == 0) nrm[r0 + j] = acc;
    }
  }
}

// ---- main: fused dual-GEMM (x:K=256, y:K=128) + max-first lse epilogue ----
// 256x128 tile, 8 waves (4 wm x 2 wn), wave tile 64x64, 16 MFMA per chunk/wave.
// LDS-read traffic per output HALVED vs the 128x128 structure (the R7 bottleneck):
// frag reads 64KB per 256x128-chunk vs 48KB per 128x128-chunk.
// K-loop discipline unchanged (R3-verified): chunk kc in buffer kc&3 (4 x 24KB),
// STAGE 3 ahead (9 loads in flight), one barrier/chunk, counted vmcnt (6/3/0),
// setprio around the MFMA cluster. NO device-scope fences (R4 lesson).
// 1 block/CU (96KB LDS, ~200 VGPR); occupancy risk accepted as the experiment.
// XCD swizzle: xcd=b&7; bm fast-varying so each XCD's A set + B slice stay L2-hot.
__global__ __launch_bounds__(512, 2) void mie_main(const char* __restrict__ ws,
                                                   float* __restrict__ part) {
  __shared__ __align__(16) char smem[98304];

  const int tid  = threadIdx.x;
  const int lane = tid & 63;
  const int wave = tid >> 6;
  const int c    = lane & 15;
  const int q    = lane >> 4;
  const int wm   = wave >> 1;   // 0..3: rows wm*64
  const int wn   = wave & 1;    // 0..1: cols wn*64

  const int b     = blockIdx.x;          // 0..1023
  const int xcd   = b & 7;
  const int w     = b >> 3;              // 0..127
  const int bm_t  = w & 15;              // fast: A streams, stays L2-resident
  const int sn_t  = xcd * 8 + (w >> 4);  // 0..63
  const int bm0   = bm_t * BM;
  const int sn0   = sn_t * BN;

  const char* xh  = ws + OFF_XH;
  const char* yh  = ws + OFF_YH;
  const char* sxh = ws + OFF_SXH;
  const char* syh = ws + OFF_SYH;
  const float* nx  = (const float*)(ws + OFF_NX);
  const float* ny  = (const float*)(ws + OFF_NY);
  const float* nsx = (const float*)(ws + OFF_NSX);
  const float* nsy = (const float*)(ws + OFF_NSY);

  // staging: thread tid carries 3 granules: A row rA, A row rA+128, B row rA.
  // (row+128 keeps the same swizzle: ((r+128)>>1)&3 == (r>>1)&3.)
  const int rA = tid >> 2;               // 0..127
  const int sg = (tid & 3) ^ ((rA >> 1) & 3);
  const char* aXp = xh  + (size_t)(bm0 + rA) * 512 + sg * 16;
  const char* aYp = yh  + (size_t)(bm0 + rA) * 256 + sg * 16;
  const char* bXp = sxh + (size_t)(sn0 + rA) * 512 + sg * 16;
  const char* bYp = syh + (size_t)(sn0 + rA) * 256 + sg * 16;
  char* sdst = smem + wave * 1024;   // + buf*24576 (+ lane*16 by gl2lds)

  // fragment LDS offsets (row stride 64 B, swizzled slot); A rows 0..255 in
  // [0,16384), B rows 0..127 in [16384,24576).
  const int slot = (q ^ ((c >> 1) & 3)) * 16;
  int aoff[4], boff[4];
  #pragma unroll
  for (int i = 0; i < 4; ++i) aoff[i] = (wm * 64 + i * 16 + c) * 64 + slot;
  #pragma unroll
  for (int j = 0; j < 4; ++j) boff[j] = 16384 + (wn * 64 + j * 16 + c) * 64 + slot;

  f32x4 accx[4][4], accy[4][4];
  #pragma unroll
  for (int i = 0; i < 4; ++i)
    #pragma unroll
    for (int j = 0; j < 4; ++j) {
      accx[i][j] = (f32x4){0.f,0.f,0.f,0.f};
      accy[i][j] = (f32x4){0.f,0.f,0.f,0.f};
    }

#define STAGE(kc) do {                                                      \
    char* _d = sdst + ((kc) & 3) * 24576;                                   \
    if ((kc) < 8) {                                                         \
      gl2lds16(aXp + (kc) * 64,         _d);                                \
      gl2lds16(aXp + 65536 + (kc) * 64, _d + 8192);                         \
      gl2lds16(bXp + (kc) * 64,         _d + 16384);                        \
    } else {                                                                \
      gl2lds16(aYp + ((kc) - 8) * 64,         _d);                          \
      gl2lds16(aYp + 32768 + ((kc) - 8) * 64, _d + 8192);                   \
      gl2lds16(bYp + ((kc) - 8) * 64,         _d + 16384);                  \
    }                                                                       \
  } while (0)

#define MFMA16(ACC, A0, A1, A2, A3, B0, B1, B2, B3) do {                          \
    ACC[0][0] = __builtin_amdgcn_mfma_f32_16x16x32_bf16(A0, B0, ACC[0][0], 0,0,0); \
    ACC[0][1] = __builtin_amdgcn_mfma_f32_16x16x32_bf16(A0, B1, ACC[0][1], 0,0,0); \
    ACC[0][2] = __builtin_amdgcn_mfma_f32_16x16x32_bf16(A0, B2, ACC[0][2], 0,0,0); \
    ACC[0][3] = __builtin_amdgcn_mfma_f32_16x16x32_bf16(A0, B3, ACC[0][3], 0,0,0); \
    ACC[1][0] = __builtin_amdgcn_mfma_f32_16x16x32_bf16(A1, B0, ACC[1][0], 0,0,0); \
    ACC[1][1] = __builtin_amdgcn_mfma_f32_16x16x32_bf16(A1, B1, ACC[1][1], 0,0,0); \
    ACC[1][2] = __builtin_amdgcn_mfma_f32_16x16x32_bf16(A1, B2, ACC[1][2], 0,0,0); \
    ACC[1][3] = __builtin_amdgcn_mfma_f32_16x16x32_bf16(A1, B3, ACC[1][3], 0,0,0); \
    ACC[2][0] = __builtin_amdgcn_mfma_f32_16x16x32_bf16(A2, B0, ACC[2][0], 0,0,0); \
    ACC[2][1] = __builtin_amdgcn_mfma_f32_16x16x32_bf16(A2, B1, ACC[2][1], 0,0,0); \
    ACC[2][2] = __builtin_amdgcn_mfma_f32_16x16x32_bf16(A2, B2, ACC[2][2], 0,0,0); \
    ACC[2][3] = __builtin_amdgcn_mfma_f32_16x16x32_bf16(A2, B3, ACC[2][3], 0,0,0); \
    ACC[3][0] = __builtin_amdgcn_mfma_f32_16x16x32_bf16(A3, B0, ACC[3][0], 0,0,0); \
    ACC[3][1] = __builtin_amdgcn_mfma_f32_16x16x32_bf16(A3, B1, ACC[3][1], 0,0,0); \
    ACC[3][2] = __builtin_amdgcn_mfma_f32_16x16x32_bf16(A3, B2, ACC[3][2], 0,0,0); \
    ACC[3][3] = __builtin_amdgcn_mfma_f32_16x16x32_bf16(A3, B3, ACC[3][3], 0,0,0); \
  } while (0)

  // vm certifies stage(kc): at the wait, outstanding = stages kc..min(kc+2,11)
  // x3 loads. kc<=9 -> 9 outstanding, certify oldest 3 -> vm=6; kc=10 -> 3; kc=11 -> 0.
#define ITER(kc, vm, ACC) do {                                              \
    asm volatile("s_waitcnt vmcnt(" #vm ")" ::: "memory");                  \
    __builtin_amdgcn_s_barrier();                                           \
    asm volatile("" ::: "memory");                                          \
    const char* _base = smem + ((kc) & 3) * 24576;                          \
    bf16x8 _A0 = *(const bf16x8*)(_base + aoff[0]);                         \
    bf16x8 _A1 = *(const bf16x8*)(_base + aoff[1]);                         \
    bf16x8 _A2 = *(const bf16x8*)(_base + aoff[2]);                         \
    bf16x8 _A3 = *(const bf16x8*)(_base + aoff[3]);                         \
    bf16x8 _B0 = *(const bf16x8*)(_base + boff[0]);                         \
    bf16x8 _B1 = *(const bf16x8*)(_base + boff[1]);                         \
    bf16x8 _B2 = *(const bf16x8*)(_base + boff[2]);                         \
    bf16x8 _B3 = *(const bf16x8*)(_base + boff[3]);                         \
    if ((kc) + 3 < 12) STAGE((kc) + 3);                                     \
    __builtin_amdgcn_s_setprio(1);                                          \
    MFMA16(ACC, _A0, _A1, _A2, _A3, _B0, _B1, _B2, _B3);                    \
    __builtin_amdgcn_s_setprio(0);                                          \
  } while (0)

  STAGE(0); STAGE(1); STAGE(2);          // 9 loads/thread in flight

  ITER(0, 6, accx);  ITER(1, 6, accx);  ITER(2, 6, accx);  ITER(3, 6, accx);
  ITER(4, 6, accx);  ITER(5, 6, accx);  ITER(6, 6, accx);  ITER(7, 6, accx);
  ITER(8, 6, accy);  ITER(9, 6, accy);  ITER(10, 3, accy); ITER(11, 0, accy);

#undef ITER
#undef MFMA16
#undef STAGE

  // buffers become the epilogue table -> fence all waves' reads first.
  __syncthreads();

  // ---- epilogue: v = acc - 0.5*(||a||^2 + ||b||^2); max-first lse ----
  float hsxv[4], hsyv[4];
  #pragma unroll
  for (int j = 0; j < 4; ++j) {
    int cc = sn0 + wn * 64 + j * 16 + c;
    hsxv[j] = -0.5f * nsx[cc];
    hsyv[j] = -0.5f * nsy[cc];
  }

  float2* xch2 = (float2*)smem;   // [3][256][16] float2 = 96 KB (exact fit)
  #pragma unroll
  for (int i = 0; i < 4; ++i) {
    #pragma unroll
    for (int rr4 = 0; rr4 < 4; ++rr4) {
      int rowg = wm * 64 + i * 16 + q * 4 + rr4;     // 0..255 local row
      float hx = -0.5f * nx[bm0 + rowg];
      float hy = -0.5f * ny[bm0 + rowg];
      float vx[4], vy[4];
      #pragma unroll
      for (int j = 0; j < 4; ++j) {
        vx[j] = accx[i][j][rr4] + hx + hsxv[j];
        vy[j] = accy[i][j][rr4] + hy + hsyv[j];
      }
      #pragma unroll
      for (int st = 0; st < 3; ++st) {
        float v0 = (st == 0) ? vx[0] + vy[0] : (st == 1 ? vx[0] : vy[0]);
        float v1 = (st == 0) ? vx[1] + vy[1] : (st == 1 ? vx[1] : vy[1]);
        float v2 = (st == 0) ? vx[2] + vy[2] : (st == 1 ? vx[2] : vy[2]);
        float v3 = (st == 0) ? vx[3] + vy[3] : (st == 1 ? vx[3] : vy[3]);
        float m = fmaxf(fmaxf(v0, v1), fmaxf(v2, v3));
        float s = __expf(v0 - m) + __expf(v1 - m) + __expf(v2 - m) + __expf(v3 - m);
        // merge lanes c and c^8 (same rowg: xor-8 stays within the q group)
        float mo = __shfl_xor(m, 8);
        float so = __shfl_xor(s, 8);
        float nm = fmaxf(m, mo);
        float ns = s * __expf(m - nm) + so * __expf(mo - nm);
        if (c < 8) xch2[(st * 256 + rowg) * 16 + wn * 8 + c] = (float2){nm, ns};
      }
    }
  }
  __syncthreads();

  // merge the 16 lane-partials per (stream,row); write coalesced [3][64][4096]
  for (int pid = tid; pid < 768; pid += 512) {
    int st = pid >> 8;
    int rl = pid & 255;
    const float2* row = xch2 + (st * 256 + rl) * 16;
    int p0 = rl & 15;                 // rotate read order
    float2 a = row[p0];
    float m = a.x, s = a.y;
    #pragma unroll
    for (int p = 1; p < 16; ++p) {
      float2 e = row[(p0 + p) & 15];
      float nm = fmaxf(m, e.x);
      s = s * __expf(m - nm) + e.y * __expf(e.x - nm);
      m = nm;
    }
    size_t idx = ((size_t)st * 64 + sn_t) * B_N + (bm0 + rl);
    ((float2*)part)[idx] = (float2){m, s};
  }
}

// ---- finalize (fin1+fin2 fused): per-row lse over 64 partials; block sums
// combined via device-scope atomics (only 64 blocks -> 64 fences, cheap).
__global__ __launch_bounds__(256) void fin_all(const float* __restrict__ part,
                                               char* __restrict__ ws,
                                               float* __restrict__ out) {
  __shared__ float2 lds[3][4][64];
  int tid  = threadIdx.x;
  int wave = tid >> 6;
  int lane = tid & 63;
  int row  = blockIdx.x * 64 + lane;
  #pragma unroll
  for (int j = 0; j < 3; ++j) {
    float m = -__builtin_inff(), s = 0.f;
    #pragma unroll
    for (int pp = 0; pp < 16; ++pp) {
      int p = wave * 16 + pp;
      float2 a = ((const float2*)part)[((size_t)j * 64 + p) * B_N + row];
      float nm = fmaxf(m, a.x);
      s = s * __expf(m - nm) + a.y * __expf(a.x - nm);
      m = nm;
    }
    lds[j][wave][lane] = (float2){m, s};
  }
  __syncthreads();
  if (wave == 0) {
    float v[3];
    #pragma unroll
    for (int j = 0; j < 3; ++j) {
      float m = -__builtin_inff(), s = 0.f;
      #pragma unroll
      for (int u = 0; u < 4; ++u) {
        float2 a = lds[j][u][lane];
        float nm = fmaxf(m, a.x);
        s = s * __expf(m - nm) + a.y * __expf(a.x - nm);
        m = nm;
      }
      v[j] = m + __logf(s);
    }
    float local = v[0] - v[1] - v[2];
    #pragma unroll
    for (int o = 32; o > 0; o >>= 1) local += __shfl_down(local, o);
    if (lane == 0) {
      unsigned* done = (unsigned*)(ws + OFF_BSUM);
      float*    fsum = (float*)(done + 1);
      atomicAdd(fsum, local);
      __threadfence();
      unsigned old = atomicAdd(done, 1u);
      if (old == 63u) {
        __threadfence();
        float tot = atomicAdd(fsum, 0.0f);   // atomic read of completed sum
        out[0] = tot * (1.0f / (float)B_N);
      }
    }
  }
}

extern "C" void kernel_launch(void* const* d_in, const int* in_sizes, int n_in,
                              void* d_out, int out_size, void* d_ws, size_t ws_size,
                              hipStream_t stream) {
  (void)in_sizes; (void)n_in; (void)out_size; (void)ws_size;
  const float* x  = (const float*)d_in[0];
  const float* y  = (const float*)d_in[1];
  const float* xs = (const float*)d_in[2];
  const float* ys = (const float*)d_in[3];
  char* ws = (char*)d_ws;

  conv_all<<<1536, 256, 0, stream>>>(x, y, xs, ys, ws);
  mie_main<<<1024, 512, 0, stream>>>(ws, (float*)(ws + OFF_PART));
  fin_all<<<B_N / 64, 256, 0, stream>>>((const float*)(ws + OFF_PART), ws, (float*)d_out);
}

// Round 10
// 130.756 us; speedup vs baseline: 1.0865x; 1.0865x over previous
//
#include <hip/hip_runtime.h>
#include <hip/hip_bf16.h>
#include <stdint.h>

// Problem dims (fixed by setup_inputs)
#define B_N 4096
#define S_N 8192
#define KX  256
#define KY  128
// Tiling: 128x128 (batch x sample) tile per block, K fused (256 x + 128 y), BK=32
#define BM 128
#define BN 128

typedef __bf16 bf16x8 __attribute__((ext_vector_type(8)));
typedef float  f32x4  __attribute__((ext_vector_type(4)));

// ---- workspace byte offsets ----
#define OFF_XH   ((size_t)0)            // 4096*256*2 = 2 MB
#define OFF_YH   ((size_t)2097152)      // 4096*128*2 = 1 MB
#define OFF_SXH  ((size_t)3145728)      // 8192*256*2 = 4 MB
#define OFF_SYH  ((size_t)7340032)      // 8192*128*2 = 2 MB
#define OFF_NX   ((size_t)9437184)      // 4096 f32
#define OFF_NY   (OFF_NX + 16384)
#define OFF_NSX  (OFF_NY + 16384)       // 8192 f32
#define OFF_NSY  (OFF_NSX + 32768)
#define OFF_PART (OFF_NSY + 32768)      // [3][64][4096] float2 = 6.29 MB
#define OFF_BSUM (OFF_PART + (size_t)3*64*4096*2*4)   // [0]=done u32, [1]=fsum f32

__device__ __forceinline__ void gl2lds16(const void* g, void* l) {
  // async global->LDS, 16B per lane; LDS dest = wave-uniform base + lane*16
  typedef const __attribute__((address_space(1))) unsigned int* gp_t;
  typedef __attribute__((address_space(3))) unsigned int* lp_t;
  __builtin_amdgcn_global_load_lds((gp_t)g, (lp_t)l, 16, 0, 0);
}

__device__ __forceinline__ unsigned short f2bf(float f) {
  unsigned u = __builtin_bit_cast(unsigned, f);
  return (unsigned short)((u + 0x7fffu + ((u >> 16) & 1u)) >> 16);
}

// ---- preprocessing v2: fp32 -> bf16 + fp32 row norms, 4 rows/wave ILP ----
__global__ __launch_bounds__(256) void conv_all(const float* __restrict__ x,
                                                const float* __restrict__ y,
                                                const float* __restrict__ xs,
                                                const float* __restrict__ ys,
                                                char* __restrict__ ws) {
  int b    = blockIdx.x;
  int wave = threadIdx.x >> 6;
  int lane = threadIdx.x & 63;
  if (b == 0 && threadIdx.x < 2) ((unsigned*)(ws + OFF_BSUM))[threadIdx.x] = 0u;
  const float* src; unsigned short* hi; float* nrm;
  int K, r0;
  if (b < 256) {
    src = x;  hi = (unsigned short*)(ws + OFF_XH);
    nrm = (float*)(ws + OFF_NX);  K = 256; r0 = b * 16 + wave * 4;
  } else if (b < 512) {
    src = y;  hi = (unsigned short*)(ws + OFF_YH);
    nrm = (float*)(ws + OFF_NY);  K = 128; r0 = (b - 256) * 16 + wave * 4;
  } else if (b < 1024) {
    src = xs; hi = (unsigned short*)(ws + OFF_SXH);
    nrm = (float*)(ws + OFF_NSX); K = 256; r0 = (b - 512) * 16 + wave * 4;
  } else {
    src = ys; hi = (unsigned short*)(ws + OFF_SYH);
    nrm = (float*)(ws + OFF_NSY); K = 128; r0 = (b - 1024) * 16 + wave * 4;
  }
  if (K == 256) {
    float4 v[4];
    #pragma unroll
    for (int j = 0; j < 4; ++j)
      v[j] = ((const float4*)(src + (size_t)(r0 + j) * 256))[lane];
    #pragma unroll
    for (int j = 0; j < 4; ++j) {
      float vv[4] = {v[j].x, v[j].y, v[j].z, v[j].w};
      ushort4 h4;
      unsigned short* hp = (unsigned short*)&h4;
      float acc = 0.f;
      #pragma unroll
      for (int k = 0; k < 4; ++k) {
        hp[k] = f2bf(vv[k]);
        acc = fmaf(vv[k], vv[k], acc);
      }
      ((ushort4*)(hi + (size_t)(r0 + j) * 256))[lane] = h4;
      #pragma unroll
      for (int o = 32; o > 0; o >>= 1) acc += __shfl_down(acc, o);
      if (lane == 0) nrm[r0 + j] = acc;
    }
  } else {
    float2 v[4];
    #pragma unroll
    for (int j = 0; j < 4; ++j)
      v[j] = ((const float2*)(src + (size_t)(r0 + j) * 128))[lane];
    #pragma unroll
    for (int j = 0; j < 4; ++j) {
      float vv[2] = {v[j].x, v[j].y};
      ushort2 h2;
      unsigned short* hp = (unsigned short*)&h2;
      float acc = 0.f;
      #pragma unroll
      for (int k = 0; k < 2; ++k) {
        hp[k] = f2bf(vv[k]);
        acc = fmaf(vv[k], vv[k], acc);
      }
      ((ushort2*)(hi + (size_t)(r0 + j) * 128))[lane] = h2;
      #pragma unroll
      for (int o = 32; o > 0; o >>= 1) acc += __shfl_down(acc, o);
      if (lane == 0) nrm[r0 + j] = acc;
    }
  }
}

// ---- main: fused dual-GEMM (x:K=256, y:K=128) + max-first lse epilogue ----
// R7 tile (128x128, 8 waves 4x2, 4x16KB buffers, 2 blocks/CU) with PAIRED K-loop:
// two chunks per barrier interval. Pair t (chunks 2t,2t+1):
//   vmcnt(0)  -- certifies stages 2t,2t+1 (issued one full pair earlier, ~free)
//   s_barrier
//   STAGE(2t+2); STAGE(2t+3)  -- into bufs of chunks 2t-2,2t-1 (consumed in pair
//     t-1; every wave's reads retired before its MFMA issue, which precedes this
//     barrier -> no WAR race). Earliest-possible issue = max latency hiding.
//   frags(2t)+MFMA8 ; frags(2t+1)+MFMA8
// 6 barriers + 6 waits per block vs R7's 12+12. R8 lesson: keep 2 blocks/CU.
// NO device-scope fences (R4 lesson).
__global__ __launch_bounds__(512, 4) void mie_main(const char* __restrict__ ws,
                                                   float* __restrict__ part) {
  __shared__ __align__(16) char smem[65536];

  const int tid  = threadIdx.x;
  const int lane = tid & 63;
  const int wave = tid >> 6;
  const int c    = lane & 15;
  const int q    = lane >> 4;
  const int wm   = wave >> 1;   // 0..3
  const int wn   = wave & 1;    // 0..1

  const int b     = blockIdx.x;
  const int xcd   = b & 7;
  const int w     = b >> 3;              // 0..255
  const int bm_t  = w & 31;              // fast: A streams, stays L2-resident
  const int sn_t  = xcd * 8 + (w >> 5);  // 0..63
  const int bm0   = bm_t * BM;
  const int sn0   = sn_t * BN;

  const char* xh  = ws + OFF_XH;
  const char* yh  = ws + OFF_YH;
  const char* sxh = ws + OFF_SXH;
  const char* syh = ws + OFF_SYH;
  const float* nx  = (const float*)(ws + OFF_NX);
  const float* ny  = (const float*)(ws + OFF_NY);
  const float* nsx = (const float*)(ws + OFF_NSX);
  const float* nsy = (const float*)(ws + OFF_NSY);

  // staging: thread tid carries granule g of row r for both A and B sides.
  const int r  = tid >> 2;
  const int sg = (tid & 3) ^ ((r >> 1) & 3);
  const char* aXp = xh  + (size_t)(bm0 + r) * 512 + sg * 16;
  const char* aYp = yh  + (size_t)(bm0 + r) * 256 + sg * 16;
  const char* bXp = sxh + (size_t)(sn0 + r) * 512 + sg * 16;
  const char* bYp = syh + (size_t)(sn0 + r) * 256 + sg * 16;
  char* sdst = smem + wave * 1024;   // + buf*16384; gl2lds adds lane*16

  // fragment LDS offsets (row stride 64 B, swizzled slot)
  const int slot  = (q ^ ((c >> 1) & 3)) * 16;
  const int aoff0 = (wm * 32 +  0 + c) * 64 + slot;
  const int aoff1 = (wm * 32 + 16 + c) * 64 + slot;
  const int boff0 = (wn * 64 +  0 + c) * 64 + slot;
  const int boff1 = (wn * 64 + 16 + c) * 64 + slot;
  const int boff2 = (wn * 64 + 32 + c) * 64 + slot;
  const int boff3 = (wn * 64 + 48 + c) * 64 + slot;

  f32x4 accx[2][4], accy[2][4];
  #pragma unroll
  for (int i = 0; i < 2; ++i)
    #pragma unroll
    for (int j = 0; j < 4; ++j) {
      accx[i][j] = (f32x4){0.f,0.f,0.f,0.f};
      accy[i][j] = (f32x4){0.f,0.f,0.f,0.f};
    }

#define STAGE(kc) do {                                                      \
    const char* _sa; const char* _sb;                                       \
    if ((kc) < 8) { _sa = aXp + (kc) * 64;       _sb = bXp + (kc) * 64; }   \
    else          { _sa = aYp + ((kc) - 8) * 64; _sb = bYp + ((kc) - 8) * 64; } \
    char* _d = sdst + ((kc) & 3) * 16384;                                   \
    gl2lds16(_sa, _d);                                                      \
    gl2lds16(_sb, _d + 8192);                                               \
  } while (0)

#define MFMA8(ACC, A0, A1, B0, B1, B2, B3) do {                                   \
    ACC[0][0] = __builtin_amdgcn_mfma_f32_16x16x32_bf16(A0, B0, ACC[0][0], 0,0,0); \
    ACC[0][1] = __builtin_amdgcn_mfma_f32_16x16x32_bf16(A0, B1, ACC[0][1], 0,0,0); \
    ACC[0][2] = __builtin_amdgcn_mfma_f32_16x16x32_bf16(A0, B2, ACC[0][2], 0,0,0); \
    ACC[0][3] = __builtin_amdgcn_mfma_f32_16x16x32_bf16(A0, B3, ACC[0][3], 0,0,0); \
    ACC[1][0] = __builtin_amdgcn_mfma_f32_16x16x32_bf16(A1, B0, ACC[1][0], 0,0,0); \
    ACC[1][1] = __builtin_amdgcn_mfma_f32_16x16x32_bf16(A1, B1, ACC[1][1], 0,0,0); \
    ACC[1][2] = __builtin_amdgcn_mfma_f32_16x16x32_bf16(A1, B2, ACC[1][2], 0,0,0); \
    ACC[1][3] = __builtin_amdgcn_mfma_f32_16x16x32_bf16(A1, B3, ACC[1][3], 0,0,0); \
  } while (0)

  // one sub-chunk: 6 ds_reads + 8 MFMAs from buffer kc&3
#define SUBCHUNK(kc, ACC) do {                                              \
    const char* _base = smem + ((kc) & 3) * 16384;                          \
    bf16x8 _A0 = *(const bf16x8*)(_base + aoff0);                           \
    bf16x8 _A1 = *(const bf16x8*)(_base + aoff1);                           \
    bf16x8 _B0 = *(const bf16x8*)(_base + 8192 + boff0);                    \
    bf16x8 _B1 = *(const bf16x8*)(_base + 8192 + boff1);                    \
    bf16x8 _B2 = *(const bf16x8*)(_base + 8192 + boff2);                    \
    bf16x8 _B3 = *(const bf16x8*)(_base + 8192 + boff3);                    \
    __builtin_amdgcn_s_setprio(1);                                          \
    MFMA8(ACC, _A0, _A1, _B0, _B1, _B2, _B3);                               \
    __builtin_amdgcn_s_setprio(0);                                          \
  } while (0)

  // pair t: chunks 2t,2t+1; stage 2t+2,2t+3 (skipped on last pair)
#define PAIR(t, ACCa, ACCb) do {                                            \
    asm volatile("s_waitcnt vmcnt(0)" ::: "memory");                        \
    __builtin_amdgcn_s_barrier();                                           \
    asm volatile("" ::: "memory");                                          \
    if (2 * (t) + 3 < 12) { STAGE(2 * (t) + 2); STAGE(2 * (t) + 3); }       \
    SUBCHUNK(2 * (t),     ACCa);                                            \
    SUBCHUNK(2 * (t) + 1, ACCb);                                            \
  } while (0)

  STAGE(0); STAGE(1);                    // depth = one pair (4 loads)

  PAIR(0, accx, accx);  PAIR(1, accx, accx);
  PAIR(2, accx, accx);  PAIR(3, accx, accx);
  PAIR(4, accy, accy);  PAIR(5, accy, accy);

#undef PAIR
#undef SUBCHUNK
#undef MFMA8
#undef STAGE

  // buffers become the epilogue LDS table -> fence all waves' reads first.
  __syncthreads();

  // ---- epilogue: v = acc - 0.5*(||a||^2 + ||b||^2); max-first lse ----
  float hxv[2][4], hyv[2][4];
  #pragma unroll
  for (int i = 0; i < 2; ++i)
    #pragma unroll
    for (int rr4 = 0; rr4 < 4; ++rr4) {
      int rr = bm0 + wm * 32 + i * 16 + q * 4 + rr4;
      hxv[i][rr4] = -0.5f * nx[rr];
      hyv[i][rr4] = -0.5f * ny[rr];
    }
  float hsxv[4], hsyv[4];
  #pragma unroll
  for (int j = 0; j < 4; ++j) {
    int cc = sn0 + wn * 64 + j * 16 + c;
    hsxv[j] = -0.5f * nsx[cc];
    hsyv[j] = -0.5f * nsy[cc];
  }

  float2* xch2 = (float2*)smem;   // [3][128][16] float2 = 48 KB
  #pragma unroll
  for (int i = 0; i < 2; ++i) {
    #pragma unroll
    for (int rr4 = 0; rr4 < 4; ++rr4) {
      float vx[4], vy[4];
      #pragma unroll
      for (int j = 0; j < 4; ++j) {
        vx[j] = accx[i][j][rr4] + hxv[i][rr4] + hsxv[j];
        vy[j] = accy[i][j][rr4] + hyv[i][rr4] + hsyv[j];
      }
      int rl = wm * 32 + i * 16 + q * 4 + rr4;
      #pragma unroll
      for (int st = 0; st < 3; ++st) {
        float v0 = (st == 0) ? vx[0] + vy[0] : (st == 1 ? vx[0] : vy[0]);
        float v1 = (st == 0) ? vx[1] + vy[1] : (st == 1 ? vx[1] : vy[1]);
        float v2 = (st == 0) ? vx[2] + vy[2] : (st == 1 ? vx[2] : vy[2]);
        float v3 = (st == 0) ? vx[3] + vy[3] : (st == 1 ? vx[3] : vy[3]);
        float m = fmaxf(fmaxf(v0, v1), fmaxf(v2, v3));
        float s = __expf(v0 - m) + __expf(v1 - m) + __expf(v2 - m) + __expf(v3 - m);
        // merge lanes c and c^8 (both halves compute identical result)
        float mo = __shfl_xor(m, 8);
        float so = __shfl_xor(s, 8);
        float nm = fmaxf(m, mo);
        float ns = s * __expf(m - nm) + so * __expf(mo - nm);
        if (c < 8) xch2[(st * 128 + rl) * 16 + wn * 8 + c] = (float2){nm, ns};
      }
    }
  }
  __syncthreads();

  // merge the 16 lane-partials per (stream,row); write coalesced [3][64][4096]
  if (tid < 384) {
    int st = tid >> 7;
    int rl = tid & 127;
    const float2* row = xch2 + (st * 128 + rl) * 16;
    int p0 = rl & 15;                 // rotate read order
    float2 a = row[p0];
    float m = a.x, s = a.y;
    #pragma unroll
    for (int p = 1; p < 16; ++p) {
      float2 e = row[(p0 + p) & 15];
      float nm = fmaxf(m, e.x);
      s = s * __expf(m - nm) + e.y * __expf(e.x - nm);
      m = nm;
    }
    size_t idx = ((size_t)st * 64 + sn_t) * B_N + (bm0 + rl);
    ((float2*)part)[idx] = (float2){m, s};
  }
}

// ---- finalize (fin1+fin2 fused): per-row lse over 64 partials; block sums
// combined via device-scope atomics (only 64 blocks -> 64 fences, cheap).
__global__ __launch_bounds__(256) void fin_all(const float* __restrict__ part,
                                               char* __restrict__ ws,
                                               float* __restrict__ out) {
  __shared__ float2 lds[3][4][64];
  int tid  = threadIdx.x;
  int wave = tid >> 6;
  int lane = tid & 63;
  int row  = blockIdx.x * 64 + lane;
  #pragma unroll
  for (int j = 0; j < 3; ++j) {
    float m = -__builtin_inff(), s = 0.f;
    #pragma unroll
    for (int pp = 0; pp < 16; ++pp) {
      int p = wave * 16 + pp;
      float2 a = ((const float2*)part)[((size_t)j * 64 + p) * B_N + row];
      float nm = fmaxf(m, a.x);
      s = s * __expf(m - nm) + a.y * __expf(a.x - nm);
      m = nm;
    }
    lds[j][wave][lane] = (float2){m, s};
  }
  __syncthreads();
  if (wave == 0) {
    float v[3];
    #pragma unroll
    for (int j = 0; j < 3; ++j) {
      float m = -__builtin_inff(), s = 0.f;
      #pragma unroll
      for (int u = 0; u < 4; ++u) {
        float2 a = lds[j][u][lane];
        float nm = fmaxf(m, a.x);
        s = s * __expf(m - nm) + a.y * __expf(a.x - nm);
        m = nm;
      }
      v[j] = m + __logf(s);
    }
    float local = v[0] - v[1] - v[2];
    #pragma unroll
    for (int o = 32; o > 0; o >>= 1) local += __shfl_down(local, o);
    if (lane == 0) {
      unsigned* done = (unsigned*)(ws + OFF_BSUM);
      float*    fsum = (float*)(done + 1);
      atomicAdd(fsum, local);
      __threadfence();
      unsigned old = atomicAdd(done, 1u);
      if (old == 63u) {
        __threadfence();
        float tot = atomicAdd(fsum, 0.0f);   // atomic read of completed sum
        out[0] = tot * (1.0f / (float)B_N);
      }
    }
  }
}

extern "C" void kernel_launch(void* const* d_in, const int* in_sizes, int n_in,
                              void* d_out, int out_size, void* d_ws, size_t ws_size,
                              hipStream_t stream) {
  (void)in_sizes; (void)n_in; (void)out_size; (void)ws_size;
  const float* x  = (const float*)d_in[0];
  const float* y  = (const float*)d_in[1];
  const float* xs = (const float*)d_in[2];
  const float* ys = (const float*)d_in[3];
  char* ws = (char*)d_ws;

  conv_all<<<1536, 256, 0, stream>>>(x, y, xs, ys, ws);
  mie_main<<<2048, 512, 0, stream>>>(ws, (float*)(ws + OFF_PART));
  fin_all<<<B_N / 64, 256, 0, stream>>>((const float*)(ws + OFF_PART), ws, (float*)d_out);
}